// Round 1
// baseline (2598.553 us; speedup 1.0000x reference)
//
#include <hip/hip_runtime.h>
#include <hip/hip_bf16.h>
#include <math.h>

#define BB 16
#define SS 512
#define HH 768
#define WW 256
#define VV 32000
#define NROWS (BB*WW)          // 4096
#define TILE_M 128
#define TILE_V 64
#define KT 32
#define NCHUNK (VV/TILE_V)     // 500
#define NMTILE (NROWS/TILE_M)  // 32
#define PPAD (TILE_M+4)        // 132 floats, keeps 16B alignment for float4 reads

// ---------------- pooling: one block per (b, w) ----------------
__global__ __launch_bounds__(256) void pool_kernel(
    const float* __restrict__ h, const int* __restrict__ wid,
    float* __restrict__ pooled)
{
    int blk = blockIdx.x;          // = b*WW + w = output row
    int b = blk >> 8;
    int w = blk & 255;
    int tid = threadIdx.x;
    __shared__ int s_wid[SS];
    for (int i = tid; i < SS; i += 256) s_wid[i] = wid[b*SS + i];
    __syncthreads();
    float a0 = 0.f, a1 = 0.f, a2 = 0.f;
    int cnt = 0;
    const float* hb = h + (size_t)b*SS*HH;
    for (int s = 0; s < SS; ++s) {
        if (s_wid[s] == w) {
            cnt++;
            const float* r = hb + (size_t)s*HH;
            a0 += r[tid]; a1 += r[tid+256]; a2 += r[tid+512];
        }
    }
    float inv = (cnt > 0) ? (1.0f / (float)cnt) : 0.0f;
    float* o = pooled + (size_t)blk*HH;
    o[tid] = a0*inv; o[tid+256] = a1*inv; o[tid+512] = a2*inv;
}

// ---------------- fused GEMM + per-chunk online softmax partials ----------------
// block: 256 threads = (tx 0..15) x (ty 0..15); tile 128 rows x 64 cols
// thread computes 8 rows x 4 cols
__global__ __launch_bounds__(256) void logits_kernel(
    const float* __restrict__ pooled, const float* __restrict__ Wc,
    const float* __restrict__ bc, const int* __restrict__ targets,
    float* __restrict__ pmax, float* __restrict__ psum,
    float* __restrict__ tlogit)
{
    const int vt = blockIdx.x;      // 0..499
    const int mt = blockIdx.y;      // 0..31
    const int tid = threadIdx.x;
    const int tx = tid & 15;
    const int ty = tid >> 4;
    const int row0 = mt * TILE_M;
    const int v0 = vt * TILE_V;

    __shared__ float PldsT[KT][PPAD];      // [k][m], padded
    __shared__ float Wlds[KT][TILE_V];     // [k][v]

    float acc[8][4];
    #pragma unroll
    for (int m = 0; m < 8; ++m)
        #pragma unroll
        for (int v = 0; v < 4; ++v) acc[m][v] = 0.f;

    for (int k0 = 0; k0 < HH; k0 += KT) {
        // P tile: 128 rows x 32 k, as float4, stored transposed
        #pragma unroll
        for (int j = 0; j < 4; ++j) {
            int flat4 = tid + j*256;        // 0..1023
            int m  = flat4 >> 3;            // 8 float4 per row
            int kq = flat4 & 7;
            float4 p4 = *(const float4*)&pooled[(size_t)(row0+m)*HH + k0 + kq*4];
            PldsT[kq*4+0][m] = p4.x;
            PldsT[kq*4+1][m] = p4.y;
            PldsT[kq*4+2][m] = p4.z;
            PldsT[kq*4+3][m] = p4.w;
        }
        // W tile: 32 k x 64 v, as float4
        #pragma unroll
        for (int j = 0; j < 2; ++j) {
            int flat4 = tid + j*256;        // 0..511
            int k  = flat4 >> 4;            // 16 float4 per row
            int vq = flat4 & 15;
            float4 w4 = *(const float4*)&Wc[(size_t)(k0+k)*VV + v0 + vq*4];
            *(float4*)&Wlds[k][vq*4] = w4;
        }
        __syncthreads();
        #pragma unroll
        for (int k = 0; k < KT; ++k) {
            float4 wv = *(const float4*)&Wlds[k][tx*4];
            float4 pa = *(const float4*)&PldsT[k][ty*8];
            float4 pb = *(const float4*)&PldsT[k][ty*8+4];
            float p[8] = {pa.x,pa.y,pa.z,pa.w,pb.x,pb.y,pb.z,pb.w};
            #pragma unroll
            for (int m = 0; m < 8; ++m) {
                acc[m][0] = fmaf(p[m], wv.x, acc[m][0]);
                acc[m][1] = fmaf(p[m], wv.y, acc[m][1]);
                acc[m][2] = fmaf(p[m], wv.z, acc[m][2]);
                acc[m][3] = fmaf(p[m], wv.w, acc[m][3]);
            }
        }
        __syncthreads();
    }

    // epilogue: add bias, per-row (64-col) max & sumexp via 16-lane shuffles
    float bias[4];
    #pragma unroll
    for (int v = 0; v < 4; ++v) bias[v] = bc[v0 + tx*4 + v];

    #pragma unroll
    for (int m = 0; m < 8; ++m) {
        const int row = row0 + ty*8 + m;
        float l[4];
        float mx = -INFINITY;
        #pragma unroll
        for (int v = 0; v < 4; ++v) {
            l[v] = acc[m][v] + bias[v];
            mx = fmaxf(mx, l[v]);
        }
        #pragma unroll
        for (int off = 1; off < 16; off <<= 1)
            mx = fmaxf(mx, __shfl_xor(mx, off, 16));
        float se = 0.f;
        #pragma unroll
        for (int v = 0; v < 4; ++v) se += __expf(l[v] - mx);
        #pragma unroll
        for (int off = 1; off < 16; off <<= 1)
            se += __shfl_xor(se, off, 16);
        if (tx == 0) {
            pmax[(size_t)row*NCHUNK + vt] = mx;
            psum[(size_t)row*NCHUNK + vt] = se;
        }
        int t = targets[row];
        int dv = t - v0;
        if (dv >= 0 && dv < TILE_V && (dv >> 2) == tx) {
            tlogit[row] = l[dv & 3];
        }
    }
}

// ---------------- combine chunk partials -> per-row loss -> atomics ----------------
__global__ __launch_bounds__(256) void reduce_kernel(
    const float* __restrict__ pmax, const float* __restrict__ psum,
    const float* __restrict__ tlogit, const int* __restrict__ targets,
    float* __restrict__ accum)
{
    const int row = blockIdx.x;
    const int tid = threadIdx.x;
    float m0 = (tid       < NCHUNK) ? pmax[(size_t)row*NCHUNK + tid]       : -INFINITY;
    float m1 = (tid + 256 < NCHUNK) ? pmax[(size_t)row*NCHUNK + tid + 256] : -INFINITY;
    float mw = fmaxf(m0, m1);
    #pragma unroll
    for (int off = 1; off < 64; off <<= 1)
        mw = fmaxf(mw, __shfl_xor(mw, off));
    __shared__ float smax[4];
    __shared__ float ssum[4];
    const int wave = tid >> 6;
    if ((tid & 63) == 0) smax[wave] = mw;
    __syncthreads();
    float mx = fmaxf(fmaxf(smax[0], smax[1]), fmaxf(smax[2], smax[3]));
    float s = 0.f;
    if (tid       < NCHUNK) s += psum[(size_t)row*NCHUNK + tid]       * __expf(m0 - mx);
    if (tid + 256 < NCHUNK) s += psum[(size_t)row*NCHUNK + tid + 256] * __expf(m1 - mx);
    #pragma unroll
    for (int off = 1; off < 64; off <<= 1)
        s += __shfl_xor(s, off);
    if ((tid & 63) == 0) ssum[wave] = s;
    __syncthreads();
    if (tid == 0) {
        float st = ssum[0] + ssum[1] + ssum[2] + ssum[3];
        float lse = mx + logf(st);
        int t = targets[row];
        if (t != 0) {  // PADDING_IDX
            atomicAdd(&accum[0], lse - tlogit[row]);
            atomicAdd(&accum[1], 1.0f);
        }
    }
}

__global__ void zero_kernel(float* accum) { accum[0] = 0.f; accum[1] = 0.f; }

__global__ void finalize_kernel(const float* __restrict__ accum, float* __restrict__ out) {
    out[0] = accum[0] / fmaxf(accum[1], 1.0f);
}

extern "C" void kernel_launch(void* const* d_in, const int* in_sizes, int n_in,
                              void* d_out, int out_size, void* d_ws, size_t ws_size,
                              hipStream_t stream) {
    const float* h       = (const float*)d_in[0];   // (16,512,768) f32
    const int*   wid     = (const int*)  d_in[1];   // (16,512) i32
    const int*   targets = (const int*)  d_in[2];   // (16,256) i32
    const float* Wc      = (const float*)d_in[3];   // (768,32000) f32
    const float* bc      = (const float*)d_in[4];   // (32000,) f32
    float* out = (float*)d_out;

    float* ws     = (float*)d_ws;
    float* pooled = ws;                              // 4096*768
    float* pmax   = pooled + (size_t)NROWS*HH;       // 4096*500
    float* psum   = pmax   + (size_t)NROWS*NCHUNK;   // 4096*500
    float* tlog   = psum   + (size_t)NROWS*NCHUNK;   // 4096
    float* accum  = tlog   + NROWS;                  // 2

    zero_kernel<<<1, 1, 0, stream>>>(accum);
    pool_kernel<<<NROWS, 256, 0, stream>>>(h, wid, pooled);
    logits_kernel<<<dim3(NCHUNK, NMTILE), 256, 0, stream>>>(
        pooled, Wc, bc, targets, pmax, psum, tlog);
    reduce_kernel<<<NROWS, 256, 0, stream>>>(pmax, psum, tlog, targets, accum);
    finalize_kernel<<<1, 1, 0, stream>>>(accum, out);
}

// Round 2
// 617.222 us; speedup vs baseline: 4.2101x; 4.2101x over previous
//
#include <hip/hip_runtime.h>
#include <math.h>

#define BB 16
#define SS 512
#define HH 768
#define WW 256
#define VV 32000
#define NROWS (BB*WW)          // 4096
#define NCHUNK 500             // 64-wide v chunks
#define BM 256
#define BN 128
#define BK 32
#define NKT (HH/BK)            // 24

typedef __attribute__((ext_vector_type(8))) short short8;
typedef __attribute__((ext_vector_type(4))) float f32x4;

__device__ __forceinline__ unsigned short f2bf(float x) {
    union { float f; unsigned int u; } c; c.f = x;
    unsigned int r = c.u + 0x7FFFu + ((c.u >> 16) & 1u);
    return (unsigned short)(r >> 16);
}

#define GLOAD16(g, l) __builtin_amdgcn_global_load_lds( \
    (const __attribute__((address_space(1))) void*)(g), \
    (__attribute__((address_space(3))) void*)(l), 16, 0, 0)

// ---------------- pooling: one block per (b, w), bf16 output ----------------
__global__ __launch_bounds__(256) void pool_kernel(
    const float* __restrict__ h, const int* __restrict__ wid,
    unsigned short* __restrict__ pooled)
{
    int blk = blockIdx.x;
    int b = blk >> 8;
    int w = blk & 255;
    int tid = threadIdx.x;
    __shared__ int s_wid[SS];
    for (int i = tid; i < SS; i += 256) s_wid[i] = wid[b*SS + i];
    __syncthreads();
    float a0 = 0.f, a1 = 0.f, a2 = 0.f;
    int cnt = 0;
    const float* hb = h + (size_t)b*SS*HH;
    for (int s = 0; s < SS; ++s) {
        if (s_wid[s] == w) {
            cnt++;
            const float* r = hb + (size_t)s*HH;
            a0 += r[tid]; a1 += r[tid+256]; a2 += r[tid+512];
        }
    }
    float inv = (cnt > 0) ? (1.0f / (float)cnt) : 0.0f;
    unsigned short* o = pooled + (size_t)blk*HH;
    o[tid]     = f2bf(a0*inv);
    o[tid+256] = f2bf(a1*inv);
    o[tid+512] = f2bf(a2*inv);
}

// ---------------- convert + transpose W: (768,32000) f32 -> (32000,768) bf16 ----------------
__global__ __launch_bounds__(256) void wt_kernel(
    const float* __restrict__ Wc, unsigned short* __restrict__ Wt)
{
    const int v0 = blockIdx.x * 64;
    const int k0 = blockIdx.y * 64;
    const int t = threadIdx.x;
    __shared__ unsigned short S[64][72];   // padded to dodge bank conflicts
    #pragma unroll
    for (int j = 0; j < 4; ++j) {
        int idx = t + j*256;               // 0..1023
        int kr = idx >> 4;                 // 0..63
        int vs = idx & 15;                 // float4 seg
        float4 f = *(const float4*)&Wc[(size_t)(k0+kr)*VV + v0 + vs*4];
        S[kr][vs*4+0] = f2bf(f.x);
        S[kr][vs*4+1] = f2bf(f.y);
        S[kr][vs*4+2] = f2bf(f.z);
        S[kr][vs*4+3] = f2bf(f.w);
    }
    __syncthreads();
    #pragma unroll
    for (int j = 0; j < 2; ++j) {
        int idx = t + j*256;               // 0..511
        int vi = idx >> 3;                 // 0..63
        int ks = idx & 7;                  // 0..7
        short8 o;
        #pragma unroll
        for (int i = 0; i < 8; ++i) o[i] = (short)S[ks*8+i][vi];
        *(short8*)&Wt[(size_t)(v0+vi)*HH + k0 + ks*8] = o;
    }
}

// ---------------- MFMA GEMM + fused per-chunk softmax partials ----------------
// 512 threads = 8 waves (4 M x 2 N), tile 256x128, wave tile 64x64
__global__ __launch_bounds__(512) void logits_kernel(
    const unsigned short* __restrict__ Pb, const unsigned short* __restrict__ Wt,
    const float* __restrict__ bc, const int* __restrict__ targets,
    float* __restrict__ pmax, float* __restrict__ psum,
    float* __restrict__ tlogit)
{
    __shared__ unsigned short Alds[2][BM*BK];   // [row][k] linear, 2x16KB
    __shared__ unsigned short Blds[2][BN*BK];   // [col][k] linear, 2x8KB

    const int t = threadIdx.x;
    const int w = t >> 6;
    const int lane = t & 63;
    const int r16 = lane & 15;
    const int kb = lane >> 4;
    const int wr = w >> 1, wc = w & 1;
    const int row0 = blockIdx.y * BM;
    const int v0 = blockIdx.x * BN;

    f32x4 acc[4][4];
    #pragma unroll
    for (int mf = 0; mf < 4; ++mf)
        #pragma unroll
        for (int nf = 0; nf < 4; ++nf)
            acc[mf][nf] = (f32x4){0.f, 0.f, 0.f, 0.f};

    int buf = 0;

    // stage(buf, kt): A tile 256x32, B tile 128x32, width-16 global_load_lds
    #define STAGE(BUF, KT) do {                                                   \
        const int k0_ = (KT) * BK;                                                \
        _Pragma("unroll")                                                         \
        for (int j = 0; j < 2; ++j) {                                             \
            int s = t + j*512;                                                    \
            int row_ = s >> 2, ks_ = s & 3;                                       \
            GLOAD16(Pb + (size_t)(row0+row_)*HH + k0_ + ks_*8,                    \
                    &Alds[BUF][(w*64 + j*512)*8]);                                \
        }                                                                         \
        {                                                                         \
            int col_ = t >> 2, ks_ = t & 3;                                       \
            GLOAD16(Wt + (size_t)(v0+col_)*HH + k0_ + ks_*8,                      \
                    &Blds[BUF][(w*64)*8]);                                        \
        }                                                                         \
    } while (0)

    STAGE(0, 0);
    __syncthreads();

    for (int kt = 0; kt < NKT; ++kt) {
        if (kt + 1 < NKT) STAGE(buf ^ 1, kt + 1);
        short8 af[4], bfv[4];
        #pragma unroll
        for (int mf = 0; mf < 4; ++mf)
            af[mf] = *(const short8*)&Alds[buf][(wr*64 + mf*16 + r16)*BK + kb*8];
        #pragma unroll
        for (int nf = 0; nf < 4; ++nf)
            bfv[nf] = *(const short8*)&Blds[buf][(wc*64 + nf*16 + r16)*BK + kb*8];
        #pragma unroll
        for (int mf = 0; mf < 4; ++mf)
            #pragma unroll
            for (int nf = 0; nf < 4; ++nf)
                acc[mf][nf] = __builtin_amdgcn_mfma_f32_16x16x32_bf16(
                    af[mf], bfv[nf], acc[mf][nf], 0, 0, 0);
        __syncthreads();
        buf ^= 1;
    }

    // epilogue: bias + per-row max/sumexp over this wave's 64 cols (one chunk)
    const int cchunk = blockIdx.x*2 + wc;
    float bias[4];
    #pragma unroll
    for (int nf = 0; nf < 4; ++nf) bias[nf] = bc[v0 + wc*64 + nf*16 + r16];

    #pragma unroll
    for (int mf = 0; mf < 4; ++mf) {
        #pragma unroll
        for (int j = 0; j < 4; ++j) {
            const int row = row0 + wr*64 + mf*16 + kb*4 + j;
            float v[4]; float mx = -INFINITY;
            #pragma unroll
            for (int nf = 0; nf < 4; ++nf) {
                v[nf] = acc[mf][nf][j] + bias[nf];
                mx = fmaxf(mx, v[nf]);
            }
            #pragma unroll
            for (int off = 1; off < 16; off <<= 1)
                mx = fmaxf(mx, __shfl_xor(mx, off, 16));
            float se = 0.f;
            #pragma unroll
            for (int nf = 0; nf < 4; ++nf) se += __expf(v[nf] - mx);
            #pragma unroll
            for (int off = 1; off < 16; off <<= 1)
                se += __shfl_xor(se, off, 16);
            if (r16 == 0) {
                pmax[(size_t)row*NCHUNK + cchunk] = mx;
                psum[(size_t)row*NCHUNK + cchunk] = se;
            }
            int tg = targets[row];
            int base = v0 + wc*64 + r16;
            #pragma unroll
            for (int nf = 0; nf < 4; ++nf)
                if (tg == base + nf*16) tlogit[row] = v[nf];
        }
    }
}

// ---------------- combine chunk partials -> per-row loss -> atomics ----------------
__global__ __launch_bounds__(256) void reduce_kernel(
    const float* __restrict__ pmax, const float* __restrict__ psum,
    const float* __restrict__ tlogit, const int* __restrict__ targets,
    float* __restrict__ accum)
{
    const int row = blockIdx.x;
    const int tid = threadIdx.x;
    float m0 = (tid       < NCHUNK) ? pmax[(size_t)row*NCHUNK + tid]       : -INFINITY;
    float m1 = (tid + 256 < NCHUNK) ? pmax[(size_t)row*NCHUNK + tid + 256] : -INFINITY;
    float mw = fmaxf(m0, m1);
    #pragma unroll
    for (int off = 1; off < 64; off <<= 1)
        mw = fmaxf(mw, __shfl_xor(mw, off));
    __shared__ float smax[4];
    __shared__ float ssum[4];
    const int wave = tid >> 6;
    if ((tid & 63) == 0) smax[wave] = mw;
    __syncthreads();
    float mx = fmaxf(fmaxf(smax[0], smax[1]), fmaxf(smax[2], smax[3]));
    float s = 0.f;
    if (tid       < NCHUNK) s += psum[(size_t)row*NCHUNK + tid]       * __expf(m0 - mx);
    if (tid + 256 < NCHUNK) s += psum[(size_t)row*NCHUNK + tid + 256] * __expf(m1 - mx);
    #pragma unroll
    for (int off = 1; off < 64; off <<= 1)
        s += __shfl_xor(s, off);
    if ((tid & 63) == 0) ssum[wave] = s;
    __syncthreads();
    if (tid == 0) {
        float st = ssum[0] + ssum[1] + ssum[2] + ssum[3];
        float lse = mx + logf(st);
        int tg = targets[row];
        if (tg != 0) {  // PADDING_IDX
            atomicAdd(&accum[0], lse - tlogit[row]);
            atomicAdd(&accum[1], 1.0f);
        }
    }
}

__global__ void zero_kernel(float* accum) { accum[0] = 0.f; accum[1] = 0.f; }

__global__ void finalize_kernel(const float* __restrict__ accum, float* __restrict__ out) {
    out[0] = accum[0] / fmaxf(accum[1], 1.0f);
}

extern "C" void kernel_launch(void* const* d_in, const int* in_sizes, int n_in,
                              void* d_out, int out_size, void* d_ws, size_t ws_size,
                              hipStream_t stream) {
    const float* h       = (const float*)d_in[0];   // (16,512,768) f32
    const int*   wid     = (const int*)  d_in[1];   // (16,512) i32
    const int*   targets = (const int*)  d_in[2];   // (16,256) i32
    const float* Wc      = (const float*)d_in[3];   // (768,32000) f32
    const float* bc      = (const float*)d_in[4];   // (32000,) f32
    float* out = (float*)d_out;

    unsigned short* pooled = (unsigned short*)d_ws;              // 4096*768 bf16
    unsigned short* Wt     = pooled + (size_t)NROWS*HH;          // 32000*768 bf16
    float* pmax  = (float*)(Wt + (size_t)HH*VV);                 // 4096*500
    float* psum  = pmax + (size_t)NROWS*NCHUNK;                  // 4096*500
    float* tlog  = psum + (size_t)NROWS*NCHUNK;                  // 4096
    float* accum = tlog + NROWS;                                 // 2

    zero_kernel<<<1, 1, 0, stream>>>(accum);
    pool_kernel<<<NROWS, 256, 0, stream>>>(h, wid, pooled);
    wt_kernel<<<dim3(VV/64, HH/64), 256, 0, stream>>>(Wc, Wt);
    logits_kernel<<<dim3(VV/BN, NROWS/BM), 512, 0, stream>>>(
        pooled, Wt, bc, targets, pmax, psum, tlog);
    reduce_kernel<<<NROWS, 256, 0, stream>>>(pmax, psum, tlog, targets, accum);
    finalize_kernel<<<1, 1, 0, stream>>>(accum, out);
}

// Round 3
// 460.308 us; speedup vs baseline: 5.6452x; 1.3409x over previous
//
#include <hip/hip_runtime.h>
#include <math.h>

#define BB 16
#define SS 512
#define HH 768
#define WW 256
#define VV 32000
#define NROWS (BB*WW)          // 4096
#define NCHUNK 500             // 64-wide v chunks
#define BM 256
#define BN 128
#define BK 32
#define NKT (HH/BK)            // 24
#define NMT (NROWS/BM)         // 16
#define NVT (VV/BN)            // 250
#define NWG (NMT*NVT)          // 4000

typedef __attribute__((ext_vector_type(8))) short short8;
typedef __attribute__((ext_vector_type(4))) float f32x4;

__device__ __forceinline__ unsigned short f2bf(float x) {
    union { float f; unsigned int u; } c; c.f = x;
    unsigned int r = c.u + 0x7FFFu + ((c.u >> 16) & 1u);
    return (unsigned short)(r >> 16);
}

#define GLOAD16(g, l) __builtin_amdgcn_global_load_lds( \
    (const __attribute__((address_space(1))) void*)(g), \
    (__attribute__((address_space(3))) void*)(l), 16, 0, 0)

// ---------------- pooling: one block per (b, w), binary search over sorted wid ----------------
__global__ __launch_bounds__(256) void pool_kernel(
    const float* __restrict__ h, const int* __restrict__ wid,
    unsigned short* __restrict__ pooled)
{
    int blk = blockIdx.x;
    int b = blk >> 8;
    int w = blk & 255;
    int tid = threadIdx.x;
    __shared__ int s_wid[SS];
    for (int i = tid; i < SS; i += 256) s_wid[i] = wid[b*SS + i];
    __syncthreads();
    // lower_bound(w), lower_bound(w+1)  (uniform across threads)
    int lo = 0, hi = SS;
    while (lo < hi) { int mid = (lo + hi) >> 1; if (s_wid[mid] < w) lo = mid + 1; else hi = mid; }
    int start = lo;
    hi = SS;
    while (lo < hi) { int mid = (lo + hi) >> 1; if (s_wid[mid] <= w) lo = mid + 1; else hi = mid; }
    int end = lo;
    int cnt = end - start;

    if (tid < 192) {
        float4 a = {0.f, 0.f, 0.f, 0.f};
        const float* hb = h + (size_t)b*SS*HH;
        for (int s = start; s < end; ++s) {
            float4 r = *(const float4*)&hb[(size_t)s*HH + tid*4];
            a.x += r.x; a.y += r.y; a.z += r.z; a.w += r.w;
        }
        float inv = (cnt > 0) ? (1.0f / (float)cnt) : 0.0f;
        ushort4 o;
        o.x = f2bf(a.x*inv); o.y = f2bf(a.y*inv);
        o.z = f2bf(a.z*inv); o.w = f2bf(a.w*inv);
        *(ushort4*)&pooled[(size_t)blk*HH + tid*4] = o;
    }
}

// ---------------- convert + transpose W: (768,32000) f32 -> (32000,768) bf16 ----------------
__global__ __launch_bounds__(256) void wt_kernel(
    const float* __restrict__ Wc, unsigned short* __restrict__ Wt)
{
    const int v0 = blockIdx.x * 64;
    const int k0 = blockIdx.y * 64;
    const int t = threadIdx.x;
    __shared__ unsigned short S[64][72];   // padded to dodge bank conflicts
    #pragma unroll
    for (int j = 0; j < 4; ++j) {
        int idx = t + j*256;               // 0..1023
        int kr = idx >> 4;                 // 0..63
        int vs = idx & 15;                 // float4 seg
        float4 f = *(const float4*)&Wc[(size_t)(k0+kr)*VV + v0 + vs*4];
        S[kr][vs*4+0] = f2bf(f.x);
        S[kr][vs*4+1] = f2bf(f.y);
        S[kr][vs*4+2] = f2bf(f.z);
        S[kr][vs*4+3] = f2bf(f.w);
    }
    __syncthreads();
    #pragma unroll
    for (int j = 0; j < 2; ++j) {
        int idx = t + j*256;               // 0..511
        int vi = idx >> 3;                 // 0..63
        int ks = idx & 7;                  // 0..7
        short8 o;
        #pragma unroll
        for (int i = 0; i < 8; ++i) o[i] = (short)S[ks*8+i][vi];
        *(short8*)&Wt[(size_t)(v0+vi)*HH + k0 + ks*8] = o;
    }
}

// ---------------- MFMA GEMM + fused per-chunk softmax partials ----------------
// 512 threads = 8 waves (4 M x 2 N), tile 256x128, wave tile 64x64
// 1D grid with bijective XCD swizzle: each XCD owns a contiguous v-range,
// m-tile-minor order -> Wt tiles stay resident in one XCD's L2.
__global__ __launch_bounds__(512) void logits_kernel(
    const unsigned short* __restrict__ Pb, const unsigned short* __restrict__ Wt,
    const float* __restrict__ bc, const int* __restrict__ targets,
    float* __restrict__ pmax, float* __restrict__ psum,
    float* __restrict__ tlogit)
{
    __shared__ unsigned short Alds[2][BM*BK];   // [row][k] linear, 2x16KB
    __shared__ unsigned short Blds[2][BN*BK];   // [col][k] linear, 2x8KB

    // XCD swizzle (NWG = 4000 divisible by 8 -> simple bijection)
    const int id = blockIdx.x;
    const int wg = (id & 7) * (NWG/8) + (id >> 3);
    const int mt = wg & (NMT-1);
    const int vt = wg >> 4;

    const int t = threadIdx.x;
    const int w = t >> 6;
    const int lane = t & 63;
    const int r16 = lane & 15;
    const int kb = lane >> 4;
    const int wr = w >> 1, wc = w & 1;
    const int row0 = mt * BM;
    const int v0 = vt * BN;

    f32x4 acc[4][4];
    #pragma unroll
    for (int mf = 0; mf < 4; ++mf)
        #pragma unroll
        for (int nf = 0; nf < 4; ++nf)
            acc[mf][nf] = (f32x4){0.f, 0.f, 0.f, 0.f};

    int buf = 0;

    #define STAGE(BUF, KT) do {                                                   \
        const int k0_ = (KT) * BK;                                                \
        _Pragma("unroll")                                                         \
        for (int j = 0; j < 2; ++j) {                                             \
            int s = t + j*512;                                                    \
            int row_ = s >> 2, ks_ = s & 3;                                       \
            GLOAD16(Pb + (size_t)(row0+row_)*HH + k0_ + ks_*8,                    \
                    &Alds[BUF][(w*64 + j*512)*8]);                                \
        }                                                                         \
        {                                                                         \
            int col_ = t >> 2, ks_ = t & 3;                                       \
            GLOAD16(Wt + (size_t)(v0+col_)*HH + k0_ + ks_*8,                      \
                    &Blds[BUF][(w*64)*8]);                                        \
        }                                                                         \
    } while (0)

    STAGE(0, 0);
    __syncthreads();

    for (int kt = 0; kt < NKT; ++kt) {
        if (kt + 1 < NKT) STAGE(buf ^ 1, kt + 1);
        short8 af[4], bfv[4];
        #pragma unroll
        for (int mf = 0; mf < 4; ++mf)
            af[mf] = *(const short8*)&Alds[buf][(wr*64 + mf*16 + r16)*BK + kb*8];
        #pragma unroll
        for (int nf = 0; nf < 4; ++nf)
            bfv[nf] = *(const short8*)&Blds[buf][(wc*64 + nf*16 + r16)*BK + kb*8];
        #pragma unroll
        for (int mf = 0; mf < 4; ++mf)
            #pragma unroll
            for (int nf = 0; nf < 4; ++nf)
                acc[mf][nf] = __builtin_amdgcn_mfma_f32_16x16x32_bf16(
                    af[mf], bfv[nf], acc[mf][nf], 0, 0, 0);
        __syncthreads();
        buf ^= 1;
    }

    // epilogue: bias + per-row max/sumexp over this wave's 64 cols (one chunk)
    const int cchunk = vt*2 + wc;
    float bias[4];
    #pragma unroll
    for (int nf = 0; nf < 4; ++nf) bias[nf] = bc[v0 + wc*64 + nf*16 + r16];

    #pragma unroll
    for (int mf = 0; mf < 4; ++mf) {
        #pragma unroll
        for (int j = 0; j < 4; ++j) {
            const int row = row0 + wr*64 + mf*16 + kb*4 + j;
            float v[4]; float mx = -INFINITY;
            #pragma unroll
            for (int nf = 0; nf < 4; ++nf) {
                v[nf] = acc[mf][nf][j] + bias[nf];
                mx = fmaxf(mx, v[nf]);
            }
            #pragma unroll
            for (int off = 1; off < 16; off <<= 1)
                mx = fmaxf(mx, __shfl_xor(mx, off, 16));
            float se = 0.f;
            #pragma unroll
            for (int nf = 0; nf < 4; ++nf) se += __expf(v[nf] - mx);
            #pragma unroll
            for (int off = 1; off < 16; off <<= 1)
                se += __shfl_xor(se, off, 16);
            if (r16 == 0) {
                pmax[(size_t)row*NCHUNK + cchunk] = mx;
                psum[(size_t)row*NCHUNK + cchunk] = se;
            }
            int tg = targets[row];
            int base = v0 + wc*64 + r16;
            #pragma unroll
            for (int nf = 0; nf < 4; ++nf)
                if (tg == base + nf*16) tlogit[row] = v[nf];
        }
    }
}

// ---------------- combine chunk partials -> per-row loss ----------------
__global__ __launch_bounds__(256) void reduce_kernel(
    const float* __restrict__ pmax, const float* __restrict__ psum,
    const float* __restrict__ tlogit, const int* __restrict__ targets,
    float* __restrict__ rowloss)
{
    const int row = blockIdx.x;
    const int tid = threadIdx.x;
    float m0 = (tid       < NCHUNK) ? pmax[(size_t)row*NCHUNK + tid]       : -INFINITY;
    float m1 = (tid + 256 < NCHUNK) ? pmax[(size_t)row*NCHUNK + tid + 256] : -INFINITY;
    float mw = fmaxf(m0, m1);
    #pragma unroll
    for (int off = 1; off < 64; off <<= 1)
        mw = fmaxf(mw, __shfl_xor(mw, off));
    __shared__ float smax[4];
    __shared__ float ssum[4];
    const int wave = tid >> 6;
    if ((tid & 63) == 0) smax[wave] = mw;
    __syncthreads();
    float mx = fmaxf(fmaxf(smax[0], smax[1]), fmaxf(smax[2], smax[3]));
    float s = 0.f;
    if (tid       < NCHUNK) s += psum[(size_t)row*NCHUNK + tid]       * __expf(m0 - mx);
    if (tid + 256 < NCHUNK) s += psum[(size_t)row*NCHUNK + tid + 256] * __expf(m1 - mx);
    #pragma unroll
    for (int off = 1; off < 64; off <<= 1)
        s += __shfl_xor(s, off);
    if ((tid & 63) == 0) ssum[wave] = s;
    __syncthreads();
    if (tid == 0) {
        float st = ssum[0] + ssum[1] + ssum[2] + ssum[3];
        float lse = mx + logf(st);
        int tg = targets[row];
        rowloss[row] = (tg != 0) ? (lse - tlogit[row]) : 0.0f;
    }
}

// ---------------- final sum over rows ----------------
__global__ __launch_bounds__(256) void finalize_kernel(
    const float* __restrict__ rowloss, const int* __restrict__ targets,
    float* __restrict__ out)
{
    const int tid = threadIdx.x;
    float s = 0.f; float c = 0.f;
    for (int i = tid; i < NROWS; i += 256) {
        s += rowloss[i];
        c += (targets[i] != 0) ? 1.0f : 0.0f;
    }
    #pragma unroll
    for (int off = 1; off < 64; off <<= 1) {
        s += __shfl_xor(s, off);
        c += __shfl_xor(c, off);
    }
    __shared__ float ss[4], sc[4];
    const int wave = tid >> 6;
    if ((tid & 63) == 0) { ss[wave] = s; sc[wave] = c; }
    __syncthreads();
    if (tid == 0) {
        float st = ss[0]+ss[1]+ss[2]+ss[3];
        float ct = sc[0]+sc[1]+sc[2]+sc[3];
        out[0] = st / fmaxf(ct, 1.0f);
    }
}

extern "C" void kernel_launch(void* const* d_in, const int* in_sizes, int n_in,
                              void* d_out, int out_size, void* d_ws, size_t ws_size,
                              hipStream_t stream) {
    const float* h       = (const float*)d_in[0];   // (16,512,768) f32
    const int*   wid     = (const int*)  d_in[1];   // (16,512) i32
    const int*   targets = (const int*)  d_in[2];   // (16,256) i32
    const float* Wc      = (const float*)d_in[3];   // (768,32000) f32
    const float* bc      = (const float*)d_in[4];   // (32000,) f32
    float* out = (float*)d_out;

    unsigned short* pooled = (unsigned short*)d_ws;              // 4096*768 bf16
    unsigned short* Wt     = pooled + (size_t)NROWS*HH;          // 32000*768 bf16
    float* pmax  = (float*)(Wt + (size_t)HH*VV);                 // 4096*500
    float* psum  = pmax + (size_t)NROWS*NCHUNK;                  // 4096*500
    float* tlog  = psum + (size_t)NROWS*NCHUNK;                  // 4096
    float* rowl  = tlog + NROWS;                                 // 4096

    pool_kernel<<<NROWS, 256, 0, stream>>>(h, wid, pooled);
    wt_kernel<<<dim3(VV/64, HH/64), 256, 0, stream>>>(Wc, Wt);
    logits_kernel<<<NWG, 512, 0, stream>>>(
        pooled, Wt, bc, targets, pmax, psum, tlog);
    reduce_kernel<<<NROWS, 256, 0, stream>>>(pmax, psum, tlog, targets, rowl);
    finalize_kernel<<<1, 256, 0, stream>>>(rowl, targets, out);
}

// Round 4
// 408.815 us; speedup vs baseline: 6.3563x; 1.1260x over previous
//
#include <hip/hip_runtime.h>
#include <math.h>

#define BB 16
#define SS 512
#define HH 768
#define WW 256
#define VV 32000
#define NROWS (BB*WW)          // 4096
#define NCHUNK 500             // 64-wide v chunks
#define BM 256
#define BN 128
#define BK 64
#define NKT (HH/BK)            // 12
#define NBUF 3
#define NMT (NROWS/BM)         // 16
#define NVT (VV/BN)            // 250
#define NWG (NMT*NVT)          // 4000

typedef __attribute__((ext_vector_type(8))) short short8;
typedef __attribute__((ext_vector_type(4))) float f32x4;

__device__ __forceinline__ unsigned short f2bf(float x) {
    union { float f; unsigned int u; } c; c.f = x;
    unsigned int r = c.u + 0x7FFFu + ((c.u >> 16) & 1u);
    return (unsigned short)(r >> 16);
}

#define GLOAD16(g, l) __builtin_amdgcn_global_load_lds( \
    (const __attribute__((address_space(1))) void*)(g), \
    (__attribute__((address_space(3))) void*)(l), 16, 0, 0)

// ---------------- pooling: one block per (b, w), binary search over sorted wid ----------------
__global__ __launch_bounds__(256) void pool_kernel(
    const float* __restrict__ h, const int* __restrict__ wid,
    unsigned short* __restrict__ pooled)
{
    int blk = blockIdx.x;
    int b = blk >> 8;
    int w = blk & 255;
    int tid = threadIdx.x;
    __shared__ int s_wid[SS];
    for (int i = tid; i < SS; i += 256) s_wid[i] = wid[b*SS + i];
    __syncthreads();
    int lo = 0, hi = SS;
    while (lo < hi) { int mid = (lo + hi) >> 1; if (s_wid[mid] < w) lo = mid + 1; else hi = mid; }
    int start = lo;
    hi = SS;
    while (lo < hi) { int mid = (lo + hi) >> 1; if (s_wid[mid] <= w) lo = mid + 1; else hi = mid; }
    int end = lo;
    int cnt = end - start;

    if (tid < 192) {
        float4 a = {0.f, 0.f, 0.f, 0.f};
        const float* hb = h + (size_t)b*SS*HH;
        for (int s = start; s < end; ++s) {
            float4 r = *(const float4*)&hb[(size_t)s*HH + tid*4];
            a.x += r.x; a.y += r.y; a.z += r.z; a.w += r.w;
        }
        float inv = (cnt > 0) ? (1.0f / (float)cnt) : 0.0f;
        ushort4 o;
        o.x = f2bf(a.x*inv); o.y = f2bf(a.y*inv);
        o.z = f2bf(a.z*inv); o.w = f2bf(a.w*inv);
        *(ushort4*)&pooled[(size_t)blk*HH + tid*4] = o;
    }
}

// ---------------- convert + transpose W: (768,32000) f32 -> (32000,768) bf16 ----------------
__global__ __launch_bounds__(256) void wt_kernel(
    const float* __restrict__ Wc, unsigned short* __restrict__ Wt)
{
    const int v0 = blockIdx.x * 64;
    const int k0 = blockIdx.y * 64;
    const int t = threadIdx.x;
    __shared__ unsigned short S[64][72];
    #pragma unroll
    for (int j = 0; j < 4; ++j) {
        int idx = t + j*256;
        int kr = idx >> 4;
        int vs = idx & 15;
        float4 f = *(const float4*)&Wc[(size_t)(k0+kr)*VV + v0 + vs*4];
        S[kr][vs*4+0] = f2bf(f.x);
        S[kr][vs*4+1] = f2bf(f.y);
        S[kr][vs*4+2] = f2bf(f.z);
        S[kr][vs*4+3] = f2bf(f.w);
    }
    __syncthreads();
    #pragma unroll
    for (int j = 0; j < 2; ++j) {
        int idx = t + j*256;
        int vi = idx >> 3;
        int ks = idx & 7;
        short8 o;
        #pragma unroll
        for (int i = 0; i < 8; ++i) o[i] = (short)S[ks*8+i][vi];
        *(short8*)&Wt[(size_t)(v0+vi)*HH + k0 + ks*8] = o;
    }
}

// ---------------- MFMA GEMM + fused per-chunk softmax partials ----------------
// 512 threads = 8 waves (4 M x 2 N), tile 256x128, BK=64, wave tile 64x64.
// 3-buffer LDS, depth-2 prefetch with counted vmcnt + raw s_barrier (T3+T4),
// XOR-swizzled LDS segs (T2, applied on global source side of global_load_lds),
// setprio around MFMA cluster (T5).
__global__ __launch_bounds__(512) void logits_kernel(
    const unsigned short* __restrict__ Pb, const unsigned short* __restrict__ Wt,
    const float* __restrict__ bc, const int* __restrict__ targets,
    float* __restrict__ pmax, float* __restrict__ psum,
    float* __restrict__ tlogit)
{
    __shared__ unsigned short Alds[NBUF][BM*BK];   // 3 x 32 KB
    __shared__ unsigned short Blds[NBUF][BN*BK];   // 3 x 16 KB

    // XCD swizzle (NWG = 4000 divisible by 8)
    const int id = blockIdx.x;
    const int wg = (id & 7) * (NWG/8) + (id >> 3);
    const int mt = wg & (NMT-1);
    const int vt = wg >> 4;

    const int t = threadIdx.x;
    const int w = t >> 6;
    const int lane = t & 63;
    const int r16 = lane & 15;
    const int kb = lane >> 4;
    const int wr = w >> 1, wc = w & 1;
    const int row0 = mt * BM;
    const int v0 = vt * BN;

    // staging lane decomposition: 8-row groups, swizzled seg
    const int rr = lane >> 3;            // 0..7 row within group
    const int gg = (lane & 7) ^ rr;      // global 16B-seg fetched into slot (lane&7)

    f32x4 acc[4][4];
    #pragma unroll
    for (int mf = 0; mf < 4; ++mf)
        #pragma unroll
        for (int nf = 0; nf < 4; ++nf)
            acc[mf][nf] = (f32x4){0.f, 0.f, 0.f, 0.f};

    // STAGE: A 256x64 (4 issues/wave), B 128x64 (2 issues/wave); 6 gload16/thread
    #define STAGE(BUF, KT) do {                                                   \
        const int k0_ = (KT) * BK;                                                \
        _Pragma("unroll")                                                         \
        for (int j = 0; j < 4; ++j) {                                             \
            int blkr = w*4 + j;  /* 8-row group 0..31 */                          \
            GLOAD16(Pb + (size_t)(row0 + blkr*8 + rr)*HH + k0_ + gg*8,            \
                    &Alds[BUF][blkr*512]);                                        \
        }                                                                         \
        _Pragma("unroll")                                                         \
        for (int j = 0; j < 2; ++j) {                                             \
            int blkc = w*2 + j;  /* 8-col group 0..15 */                          \
            GLOAD16(Wt + (size_t)(v0 + blkc*8 + rr)*HH + k0_ + gg*8,              \
                    &Blds[BUF][blkc*512]);                                        \
        }                                                                         \
    } while (0)

    STAGE(0, 0);
    STAGE(1, 1);

    for (int kt = 0; kt < NKT; ++kt) {
        // wait for STAGE(kt) (its 6 loads + possibly 6 in flight for kt+1)
        if (kt + 1 < NKT) { asm volatile("s_waitcnt vmcnt(6)" ::: "memory"); }
        else              { asm volatile("s_waitcnt vmcnt(0)" ::: "memory"); }
        __builtin_amdgcn_s_barrier();
        asm volatile("" ::: "memory");

        if (kt + 2 < NKT) STAGE((kt + 2) % NBUF, kt + 2);

        const int cb = kt % NBUF;
        const unsigned short* Ab = &Alds[cb][0];
        const unsigned short* Bb = &Blds[cb][0];

        #pragma unroll
        for (int ks = 0; ks < 2; ++ks) {
            short8 af[4], bfv[4];
            const int segbase = ks*4 + kb;
            #pragma unroll
            for (int mf = 0; mf < 4; ++mf) {
                int row = wr*64 + mf*16 + r16;
                int u = row*8 + (segbase ^ (r16 & 7));
                af[mf] = *(const short8*)&Ab[u*8];
            }
            #pragma unroll
            for (int nf = 0; nf < 4; ++nf) {
                int col = wc*64 + nf*16 + r16;
                int u = col*8 + (segbase ^ (r16 & 7));
                bfv[nf] = *(const short8*)&Bb[u*8];
            }
            __builtin_amdgcn_s_setprio(1);
            #pragma unroll
            for (int mf = 0; mf < 4; ++mf)
                #pragma unroll
                for (int nf = 0; nf < 4; ++nf)
                    acc[mf][nf] = __builtin_amdgcn_mfma_f32_16x16x32_bf16(
                        af[mf], bfv[nf], acc[mf][nf], 0, 0, 0);
            __builtin_amdgcn_s_setprio(0);
        }
    }

    // epilogue: bias + per-row max/sumexp over this wave's 64 cols (one chunk)
    const int cchunk = vt*2 + wc;
    float bias[4];
    #pragma unroll
    for (int nf = 0; nf < 4; ++nf) bias[nf] = bc[v0 + wc*64 + nf*16 + r16];

    #pragma unroll
    for (int mf = 0; mf < 4; ++mf) {
        #pragma unroll
        for (int j = 0; j < 4; ++j) {
            const int row = row0 + wr*64 + mf*16 + kb*4 + j;
            float v[4]; float mx = -INFINITY;
            #pragma unroll
            for (int nf = 0; nf < 4; ++nf) {
                v[nf] = acc[mf][nf][j] + bias[nf];
                mx = fmaxf(mx, v[nf]);
            }
            #pragma unroll
            for (int off = 1; off < 16; off <<= 1)
                mx = fmaxf(mx, __shfl_xor(mx, off, 16));
            float se = 0.f;
            #pragma unroll
            for (int nf = 0; nf < 4; ++nf) se += __expf(v[nf] - mx);
            #pragma unroll
            for (int off = 1; off < 16; off <<= 1)
                se += __shfl_xor(se, off, 16);
            if (r16 == 0) {
                pmax[(size_t)row*NCHUNK + cchunk] = mx;
                psum[(size_t)row*NCHUNK + cchunk] = se;
            }
            int tg = targets[row];
            int base = v0 + wc*64 + r16;
            #pragma unroll
            for (int nf = 0; nf < 4; ++nf)
                if (tg == base + nf*16) tlogit[row] = v[nf];
        }
    }
}

// ---------------- combine chunk partials -> per-row loss ----------------
__global__ __launch_bounds__(256) void reduce_kernel(
    const float* __restrict__ pmax, const float* __restrict__ psum,
    const float* __restrict__ tlogit, const int* __restrict__ targets,
    float* __restrict__ rowloss)
{
    const int row = blockIdx.x;
    const int tid = threadIdx.x;
    float m0 = (tid       < NCHUNK) ? pmax[(size_t)row*NCHUNK + tid]       : -INFINITY;
    float m1 = (tid + 256 < NCHUNK) ? pmax[(size_t)row*NCHUNK + tid + 256] : -INFINITY;
    float mw = fmaxf(m0, m1);
    #pragma unroll
    for (int off = 1; off < 64; off <<= 1)
        mw = fmaxf(mw, __shfl_xor(mw, off));
    __shared__ float smax[4];
    __shared__ float ssum[4];
    const int wave = tid >> 6;
    if ((tid & 63) == 0) smax[wave] = mw;
    __syncthreads();
    float mx = fmaxf(fmaxf(smax[0], smax[1]), fmaxf(smax[2], smax[3]));
    float s = 0.f;
    if (tid       < NCHUNK) s += psum[(size_t)row*NCHUNK + tid]       * __expf(m0 - mx);
    if (tid + 256 < NCHUNK) s += psum[(size_t)row*NCHUNK + tid + 256] * __expf(m1 - mx);
    #pragma unroll
    for (int off = 1; off < 64; off <<= 1)
        s += __shfl_xor(s, off);
    if ((tid & 63) == 0) ssum[wave] = s;
    __syncthreads();
    if (tid == 0) {
        float st = ssum[0] + ssum[1] + ssum[2] + ssum[3];
        float lse = mx + logf(st);
        int tg = targets[row];
        rowloss[row] = (tg != 0) ? (lse - tlogit[row]) : 0.0f;
    }
}

// ---------------- final sum over rows ----------------
__global__ __launch_bounds__(256) void finalize_kernel(
    const float* __restrict__ rowloss, const int* __restrict__ targets,
    float* __restrict__ out)
{
    const int tid = threadIdx.x;
    float s = 0.f; float c = 0.f;
    for (int i = tid; i < NROWS; i += 256) {
        s += rowloss[i];
        c += (targets[i] != 0) ? 1.0f : 0.0f;
    }
    #pragma unroll
    for (int off = 1; off < 64; off <<= 1) {
        s += __shfl_xor(s, off);
        c += __shfl_xor(c, off);
    }
    __shared__ float ss[4], sc[4];
    const int wave = tid >> 6;
    if ((tid & 63) == 0) { ss[wave] = s; sc[wave] = c; }
    __syncthreads();
    if (tid == 0) {
        float st = ss[0]+ss[1]+ss[2]+ss[3];
        float ct = sc[0]+sc[1]+sc[2]+sc[3];
        out[0] = st / fmaxf(ct, 1.0f);
    }
}

extern "C" void kernel_launch(void* const* d_in, const int* in_sizes, int n_in,
                              void* d_out, int out_size, void* d_ws, size_t ws_size,
                              hipStream_t stream) {
    const float* h       = (const float*)d_in[0];   // (16,512,768) f32
    const int*   wid     = (const int*)  d_in[1];   // (16,512) i32
    const int*   targets = (const int*)  d_in[2];   // (16,256) i32
    const float* Wc      = (const float*)d_in[3];   // (768,32000) f32
    const float* bc      = (const float*)d_in[4];   // (32000,) f32
    float* out = (float*)d_out;

    unsigned short* pooled = (unsigned short*)d_ws;              // 4096*768 bf16
    unsigned short* Wt     = pooled + (size_t)NROWS*HH;          // 32000*768 bf16
    float* pmax  = (float*)(Wt + (size_t)HH*VV);                 // 4096*500
    float* psum  = pmax + (size_t)NROWS*NCHUNK;                  // 4096*500
    float* tlog  = psum + (size_t)NROWS*NCHUNK;                  // 4096
    float* rowl  = tlog + NROWS;                                 // 4096

    pool_kernel<<<NROWS, 256, 0, stream>>>(h, wid, pooled);
    wt_kernel<<<dim3(VV/64, HH/64), 256, 0, stream>>>(Wc, Wt);
    logits_kernel<<<NWG, 512, 0, stream>>>(
        pooled, Wt, bc, targets, pmax, psum, tlog);
    reduce_kernel<<<NROWS, 256, 0, stream>>>(pmax, psum, tlog, targets, rowl);
    finalize_kernel<<<1, 256, 0, stream>>>(rowl, targets, out);
}

// Round 5
// 342.296 us; speedup vs baseline: 7.5915x; 1.1943x over previous
//
#include <hip/hip_runtime.h>
#include <math.h>

#define BB 16
#define SS 512
#define HH 768
#define WW 256
#define VV 32000
#define NROWS (BB*WW)          // 4096
#define NCHUNK 500             // 64-wide v chunks
#define BM 256
#define BN 256
#define BK 64
#define NKT (HH/BK)            // 12
#define NMT (NROWS/BM)         // 16
#define NVT (VV/BN)            // 125
#define NWG (NMT*NVT)          // 2000

typedef __attribute__((ext_vector_type(8))) short short8;
typedef __attribute__((ext_vector_type(4))) float f32x4;

__device__ __forceinline__ unsigned short f2bf(float x) {
    union { float f; unsigned int u; } c; c.f = x;
    unsigned int r = c.u + 0x7FFFu + ((c.u >> 16) & 1u);
    return (unsigned short)(r >> 16);
}

#define GLOAD16(g, l) __builtin_amdgcn_global_load_lds( \
    (const __attribute__((address_space(1))) void*)(g), \
    (__attribute__((address_space(3))) void*)(l), 16, 0, 0)

// ---------------- pooling: one block per (b, w), binary search over sorted wid ----------------
__global__ __launch_bounds__(256) void pool_kernel(
    const float* __restrict__ h, const int* __restrict__ wid,
    unsigned short* __restrict__ pooled)
{
    int blk = blockIdx.x;
    int b = blk >> 8;
    int w = blk & 255;
    int tid = threadIdx.x;
    __shared__ int s_wid[SS];
    for (int i = tid; i < SS; i += 256) s_wid[i] = wid[b*SS + i];
    __syncthreads();
    int lo = 0, hi = SS;
    while (lo < hi) { int mid = (lo + hi) >> 1; if (s_wid[mid] < w) lo = mid + 1; else hi = mid; }
    int start = lo;
    hi = SS;
    while (lo < hi) { int mid = (lo + hi) >> 1; if (s_wid[mid] <= w) lo = mid + 1; else hi = mid; }
    int end = lo;
    int cnt = end - start;

    if (tid < 192) {
        float4 a = {0.f, 0.f, 0.f, 0.f};
        const float* hb = h + (size_t)b*SS*HH;
        for (int s = start; s < end; ++s) {
            float4 r = *(const float4*)&hb[(size_t)s*HH + tid*4];
            a.x += r.x; a.y += r.y; a.z += r.z; a.w += r.w;
        }
        float inv = (cnt > 0) ? (1.0f / (float)cnt) : 0.0f;
        ushort4 o;
        o.x = f2bf(a.x*inv); o.y = f2bf(a.y*inv);
        o.z = f2bf(a.z*inv); o.w = f2bf(a.w*inv);
        *(ushort4*)&pooled[(size_t)blk*HH + tid*4] = o;
    }
}

// ---------------- convert + transpose W: (768,32000) f32 -> (32000,768) bf16 ----------------
__global__ __launch_bounds__(256) void wt_kernel(
    const float* __restrict__ Wc, unsigned short* __restrict__ Wt)
{
    const int v0 = blockIdx.x * 64;
    const int k0 = blockIdx.y * 64;
    const int t = threadIdx.x;
    __shared__ unsigned short S[64][72];
    #pragma unroll
    for (int j = 0; j < 4; ++j) {
        int idx = t + j*256;
        int kr = idx >> 4;
        int vs = idx & 15;
        float4 f = *(const float4*)&Wc[(size_t)(k0+kr)*VV + v0 + vs*4];
        S[kr][vs*4+0] = f2bf(f.x);
        S[kr][vs*4+1] = f2bf(f.y);
        S[kr][vs*4+2] = f2bf(f.z);
        S[kr][vs*4+3] = f2bf(f.w);
    }
    __syncthreads();
    #pragma unroll
    for (int j = 0; j < 2; ++j) {
        int idx = t + j*256;
        int vi = idx >> 3;
        int ks = idx & 7;
        short8 o;
        #pragma unroll
        for (int i = 0; i < 8; ++i) o[i] = (short)S[ks*8+i][vi];
        *(short8*)&Wt[(size_t)(v0+vi)*HH + k0 + ks*8] = o;
    }
}

// ---------------- MFMA GEMM, 256x256 tile, 8-phase schedule (m201 port) ----------------
// 512 threads = 8 waves (2M x 4N), wave tile 128x64.
// LDS: 2 dbuf x 2 half x (A,B), halves of 128x64 bf16 = 16 KB -> 128 KB total.
// Per K-tile: 4 phases {ds_read subtile; stage 1 half; barrier; lgkm0; 16 MFMA; barrier}.
// Stage order at tile t: ph0=A0(t+1) ph1=A1(t+1) ph2=B0(t+2) ph3=B1(t+2).
// vmcnt(4) once per tile at ph3 end (vmcnt(0) entering last tile only).
__global__ __launch_bounds__(512, 2) void logits_kernel(
    const unsigned short* __restrict__ Pb, const unsigned short* __restrict__ Wt,
    const float* __restrict__ bc, const int* __restrict__ targets,
    float* __restrict__ pmax, float* __restrict__ psum,
    float* __restrict__ tlogit)
{
    __shared__ unsigned short Alds[2][2][128*64];   // [dbuf][half][row*64+k] 64 KB
    __shared__ unsigned short Blds[2][2][128*64];   // [dbuf][half][col*64+k] 64 KB

    // XCD swizzle (NWG = 2000, divisible by 8)
    const int id = blockIdx.x;
    const int wg = (id & 7) * (NWG/8) + (id >> 3);
    const int mt = wg % NMT;
    const int vt = wg / NMT;

    const int t = threadIdx.x;
    const int w = t >> 6;
    const int lane = t & 63;
    const int r16 = lane & 15;
    const int kb = (lane >> 4) & 3;
    const int wr = w >> 2;          // 0..1
    const int wc = w & 3;           // 0..3
    const int row0 = mt * BM;
    const int v0 = vt * BN;

    // staging decomposition: 8-row groups, pre-swizzled global seg
    const int rr = lane >> 3;            // row within 8-row group
    const int gg = (lane & 7) ^ rr;      // global 16B-seg for slot (lane&7)

    #define STAGE_A(BUF, HLF, KT) do {                                            \
        _Pragma("unroll")                                                         \
        for (int j_ = 0; j_ < 2; ++j_) {                                          \
            int rg_ = w*2 + j_;                                                   \
            GLOAD16(Pb + (size_t)(row0 + (HLF)*128 + rg_*8 + rr)*HH + (KT)*BK + gg*8, \
                    &Alds[BUF][HLF][rg_*512]);                                    \
        }                                                                         \
    } while (0)

    #define STAGE_B(BUF, HLF, KT) do {                                            \
        _Pragma("unroll")                                                         \
        for (int j_ = 0; j_ < 2; ++j_) {                                          \
            int rg_ = w*2 + j_;                                                   \
            GLOAD16(Wt + (size_t)(v0 + (HLF)*128 + rg_*8 + rr)*HH + (KT)*BK + gg*8, \
                    &Blds[BUF][HLF][rg_*512]);                                    \
        }                                                                         \
    } while (0)

    // prologue: B(0), A(0), B(1)  (12 loads/thread in FIFO order)
    STAGE_B(0, 0, 0); STAGE_B(0, 1, 0);
    STAGE_A(0, 0, 0); STAGE_A(0, 1, 0);
    STAGE_B(1, 0, 1); STAGE_B(1, 1, 1);

    f32x4 acc[8][4];
    #pragma unroll
    for (int mf = 0; mf < 8; ++mf)
        #pragma unroll
        for (int nf = 0; nf < 4; ++nf)
            acc[mf][nf] = (f32x4){0.f, 0.f, 0.f, 0.f};

    asm volatile("s_waitcnt vmcnt(4)" ::: "memory");   // A(0),B(0) arrived; B(1) in flight
    __builtin_amdgcn_s_barrier();

    for (int kt = 0; kt < NKT; ++kt) {
        const int buf = kt & 1;
        const unsigned short* Abase = &Alds[buf][wr][0];
        const unsigned short* Bbase = &Blds[buf][wc >> 1][0];
        const int bcol = (wc & 1) * 64;

        short8 bfr[4][2];
        #pragma unroll
        for (int q = 0; q < 4; ++q) {
            // ---- ds-read this phase's register subtile ----
            if (q == 0) {
                #pragma unroll
                for (int nf = 0; nf < 4; ++nf)
                    #pragma unroll
                    for (int ks = 0; ks < 2; ++ks) {
                        int col = bcol + nf*16 + r16;
                        bfr[nf][ks] = *(const short8*)
                            &Bbase[col*64 + ((ks*4 + kb) ^ (r16 & 7))*8];
                    }
            }
            short8 afr[2][2];
            #pragma unroll
            for (int i = 0; i < 2; ++i)
                #pragma unroll
                for (int ks = 0; ks < 2; ++ks) {
                    int row = (q*2 + i)*16 + r16;
                    afr[i][ks] = *(const short8*)
                        &Abase[row*64 + ((ks*4 + kb) ^ (r16 & 7))*8];
                }
            asm volatile("" ::: "memory");

            // ---- stage one half-tile ----
            if      (q == 0) { if (kt + 1 < NKT) STAGE_A(buf ^ 1, 0, kt + 1); }
            else if (q == 1) { if (kt + 1 < NKT) STAGE_A(buf ^ 1, 1, kt + 1); }
            else if (q == 2) { if (kt + 2 < NKT) STAGE_B(buf,     0, kt + 2); }
            else             { if (kt + 2 < NKT) STAGE_B(buf,     1, kt + 2); }

            __builtin_amdgcn_s_barrier();
            asm volatile("s_waitcnt lgkmcnt(0)" ::: "memory");
            __builtin_amdgcn_sched_barrier(0);
            __builtin_amdgcn_s_setprio(1);
            #pragma unroll
            for (int ks = 0; ks < 2; ++ks)
                #pragma unroll
                for (int i = 0; i < 2; ++i)
                    #pragma unroll
                    for (int nf = 0; nf < 4; ++nf)
                        acc[q*2 + i][nf] = __builtin_amdgcn_mfma_f32_16x16x32_bf16(
                            afr[i][ks], bfr[nf][ks], acc[q*2 + i][nf], 0, 0, 0);
            __builtin_amdgcn_s_setprio(0);
            if (q == 3) {
                if (kt == NKT - 2)     asm volatile("s_waitcnt vmcnt(0)" ::: "memory");
                else if (kt < NKT - 2) asm volatile("s_waitcnt vmcnt(4)" ::: "memory");
            }
            __builtin_amdgcn_s_barrier();
            __builtin_amdgcn_sched_barrier(0);
        }
    }

    // epilogue: bias + per-row max/sumexp over this wave's 64 cols (one chunk)
    const int cchunk = vt*4 + wc;
    float bias[4];
    #pragma unroll
    for (int nf = 0; nf < 4; ++nf) bias[nf] = bc[v0 + wc*64 + nf*16 + r16];

    #pragma unroll
    for (int mf = 0; mf < 8; ++mf) {
        #pragma unroll
        for (int j = 0; j < 4; ++j) {
            const int row = row0 + wr*128 + mf*16 + kb*4 + j;
            float v[4]; float mx = -INFINITY;
            #pragma unroll
            for (int nf = 0; nf < 4; ++nf) {
                v[nf] = acc[mf][nf][j] + bias[nf];
                mx = fmaxf(mx, v[nf]);
            }
            #pragma unroll
            for (int off = 1; off < 16; off <<= 1)
                mx = fmaxf(mx, __shfl_xor(mx, off, 16));
            float se = 0.f;
            #pragma unroll
            for (int nf = 0; nf < 4; ++nf) se += __expf(v[nf] - mx);
            #pragma unroll
            for (int off = 1; off < 16; off <<= 1)
                se += __shfl_xor(se, off, 16);
            if (r16 == 0) {
                pmax[(size_t)row*NCHUNK + cchunk] = mx;
                psum[(size_t)row*NCHUNK + cchunk] = se;
            }
            int tg = targets[row];
            int base = v0 + wc*64 + r16;
            #pragma unroll
            for (int nf = 0; nf < 4; ++nf)
                if (tg == base + nf*16) tlogit[row] = v[nf];
        }
    }
}

// ---------------- combine chunk partials -> per-row loss ----------------
__global__ __launch_bounds__(256) void reduce_kernel(
    const float* __restrict__ pmax, const float* __restrict__ psum,
    const float* __restrict__ tlogit, const int* __restrict__ targets,
    float* __restrict__ rowloss)
{
    const int row = blockIdx.x;
    const int tid = threadIdx.x;
    float m0 = (tid       < NCHUNK) ? pmax[(size_t)row*NCHUNK + tid]       : -INFINITY;
    float m1 = (tid + 256 < NCHUNK) ? pmax[(size_t)row*NCHUNK + tid + 256] : -INFINITY;
    float mw = fmaxf(m0, m1);
    #pragma unroll
    for (int off = 1; off < 64; off <<= 1)
        mw = fmaxf(mw, __shfl_xor(mw, off));
    __shared__ float smax[4];
    __shared__ float ssum[4];
    const int wave = tid >> 6;
    if ((tid & 63) == 0) smax[wave] = mw;
    __syncthreads();
    float mx = fmaxf(fmaxf(smax[0], smax[1]), fmaxf(smax[2], smax[3]));
    float s = 0.f;
    if (tid       < NCHUNK) s += psum[(size_t)row*NCHUNK + tid]       * __expf(m0 - mx);
    if (tid + 256 < NCHUNK) s += psum[(size_t)row*NCHUNK + tid + 256] * __expf(m1 - mx);
    #pragma unroll
    for (int off = 1; off < 64; off <<= 1)
        s += __shfl_xor(s, off);
    if ((tid & 63) == 0) ssum[wave] = s;
    __syncthreads();
    if (tid == 0) {
        float st = ssum[0] + ssum[1] + ssum[2] + ssum[3];
        float lse = mx + logf(st);
        int tg = targets[row];
        rowloss[row] = (tg != 0) ? (lse - tlogit[row]) : 0.0f;
    }
}

// ---------------- final sum over rows ----------------
__global__ __launch_bounds__(256) void finalize_kernel(
    const float* __restrict__ rowloss, const int* __restrict__ targets,
    float* __restrict__ out)
{
    const int tid = threadIdx.x;
    float s = 0.f; float c = 0.f;
    for (int i = tid; i < NROWS; i += 256) {
        s += rowloss[i];
        c += (targets[i] != 0) ? 1.0f : 0.0f;
    }
    #pragma unroll
    for (int off = 1; off < 64; off <<= 1) {
        s += __shfl_xor(s, off);
        c += __shfl_xor(c, off);
    }
    __shared__ float ss[4], sc[4];
    const int wave = tid >> 6;
    if ((tid & 63) == 0) { ss[wave] = s; sc[wave] = c; }
    __syncthreads();
    if (tid == 0) {
        float st = ss[0]+ss[1]+ss[2]+ss[3];
        float ct = sc[0]+sc[1]+sc[2]+sc[3];
        out[0] = st / fmaxf(ct, 1.0f);
    }
}

extern "C" void kernel_launch(void* const* d_in, const int* in_sizes, int n_in,
                              void* d_out, int out_size, void* d_ws, size_t ws_size,
                              hipStream_t stream) {
    const float* h       = (const float*)d_in[0];   // (16,512,768) f32
    const int*   wid     = (const int*)  d_in[1];   // (16,512) i32
    const int*   targets = (const int*)  d_in[2];   // (16,256) i32
    const float* Wc      = (const float*)d_in[3];   // (768,32000) f32
    const float* bc      = (const float*)d_in[4];   // (32000,) f32
    float* out = (float*)d_out;

    unsigned short* pooled = (unsigned short*)d_ws;              // 4096*768 bf16
    unsigned short* Wt     = pooled + (size_t)NROWS*HH;          // 32000*768 bf16
    float* pmax  = (float*)(Wt + (size_t)HH*VV);                 // 4096*500
    float* psum  = pmax + (size_t)NROWS*NCHUNK;                  // 4096*500
    float* tlog  = psum + (size_t)NROWS*NCHUNK;                  // 4096
    float* rowl  = tlog + NROWS;                                 // 4096

    pool_kernel<<<NROWS, 256, 0, stream>>>(h, wid, pooled);
    wt_kernel<<<dim3(VV/64, HH/64), 256, 0, stream>>>(Wc, Wt);
    logits_kernel<<<NWG, 512, 0, stream>>>(
        pooled, Wt, bc, targets, pmax, psum, tlog);
    reduce_kernel<<<NROWS, 256, 0, stream>>>(pmax, psum, tlog, targets, rowl);
    finalize_kernel<<<1, 256, 0, stream>>>(rowl, targets, out);
}

// Round 6
// 337.010 us; speedup vs baseline: 7.7106x; 1.0157x over previous
//
#include <hip/hip_runtime.h>
#include <math.h>

#define BB 16
#define SS 512
#define HH 768
#define WW 256
#define VV 32000
#define NROWS (BB*WW)          // 4096
#define NCHUNK 500             // 64-wide v chunks
#define BM 256
#define BN 256
#define BK 64
#define NKT (HH/BK)            // 12
#define NMT (NROWS/BM)         // 16
#define NVT (VV/BN)            // 125
#define NWG (NMT*NVT)          // 2000

typedef __attribute__((ext_vector_type(8))) short short8;
typedef __attribute__((ext_vector_type(4))) float f32x4;

__device__ __forceinline__ unsigned short f2bf(float x) {
    union { float f; unsigned int u; } c; c.f = x;
    unsigned int r = c.u + 0x7FFFu + ((c.u >> 16) & 1u);
    return (unsigned short)(r >> 16);
}

#define GLOAD16(g, l) __builtin_amdgcn_global_load_lds( \
    (const __attribute__((address_space(1))) void*)(g), \
    (__attribute__((address_space(3))) void*)(l), 16, 0, 0)

// ---------------- pooling: one block per (b, w), binary search over sorted wid ----------------
__global__ __launch_bounds__(256) void pool_kernel(
    const float* __restrict__ h, const int* __restrict__ wid,
    unsigned short* __restrict__ pooled)
{
    int blk = blockIdx.x;
    int b = blk >> 8;
    int w = blk & 255;
    int tid = threadIdx.x;
    __shared__ int s_wid[SS];
    for (int i = tid; i < SS; i += 256) s_wid[i] = wid[b*SS + i];
    __syncthreads();
    int lo = 0, hi = SS;
    while (lo < hi) { int mid = (lo + hi) >> 1; if (s_wid[mid] < w) lo = mid + 1; else hi = mid; }
    int start = lo;
    hi = SS;
    while (lo < hi) { int mid = (lo + hi) >> 1; if (s_wid[mid] <= w) lo = mid + 1; else hi = mid; }
    int end = lo;
    int cnt = end - start;

    if (tid < 192) {
        float4 a = {0.f, 0.f, 0.f, 0.f};
        const float* hb = h + (size_t)b*SS*HH;
        for (int s = start; s < end; ++s) {
            float4 r = *(const float4*)&hb[(size_t)s*HH + tid*4];
            a.x += r.x; a.y += r.y; a.z += r.z; a.w += r.w;
        }
        float inv = (cnt > 0) ? (1.0f / (float)cnt) : 0.0f;
        ushort4 o;
        o.x = f2bf(a.x*inv); o.y = f2bf(a.y*inv);
        o.z = f2bf(a.z*inv); o.w = f2bf(a.w*inv);
        *(ushort4*)&pooled[(size_t)blk*HH + tid*4] = o;
    }
}

// ---------------- convert + transpose W: (768,32000) f32 -> (32000,768) bf16 ----------------
__global__ __launch_bounds__(256) void wt_kernel(
    const float* __restrict__ Wc, unsigned short* __restrict__ Wt)
{
    const int v0 = blockIdx.x * 64;
    const int k0 = blockIdx.y * 64;
    const int t = threadIdx.x;
    __shared__ unsigned short S[64][72];
    #pragma unroll
    for (int j = 0; j < 4; ++j) {
        int idx = t + j*256;
        int kr = idx >> 4;
        int vs = idx & 15;
        float4 f = *(const float4*)&Wc[(size_t)(k0+kr)*VV + v0 + vs*4];
        S[kr][vs*4+0] = f2bf(f.x);
        S[kr][vs*4+1] = f2bf(f.y);
        S[kr][vs*4+2] = f2bf(f.z);
        S[kr][vs*4+3] = f2bf(f.w);
    }
    __syncthreads();
    #pragma unroll
    for (int j = 0; j < 2; ++j) {
        int idx = t + j*256;
        int vi = idx >> 3;
        int ks = idx & 7;
        short8 o;
        #pragma unroll
        for (int i = 0; i < 8; ++i) o[i] = (short)S[ks*8+i][vi];
        *(short8*)&Wt[(size_t)(v0+vi)*HH + k0 + ks*8] = o;
    }
}

// ---------------- MFMA GEMM, 256x256 tile, 2-phase-per-K-tile schedule ----------------
// 512 threads = 8 waves (2M x 4N), wave tile 128x64.
// LDS: 2 dbuf x 2 half x (A,B) = 128 KB.
// Per K-tile: 2 phases {ds_read subtile; stage; barrier; lgkm0; 32 MFMA; barrier}.
// Stage: ph0 = A both halves (t+1), ph1 = B both halves (t+2).
// vmcnt(4) once per tile at ph1 end (vmcnt(0) entering last tile only).
__global__ __launch_bounds__(512, 2) void logits_kernel(
    const unsigned short* __restrict__ Pb, const unsigned short* __restrict__ Wt,
    const float* __restrict__ bc, const int* __restrict__ targets,
    float* __restrict__ pmax, float* __restrict__ psum,
    float* __restrict__ tlogit)
{
    __shared__ unsigned short Alds[2][2][128*64];   // [dbuf][half] 64 KB
    __shared__ unsigned short Blds[2][2][128*64];   // [dbuf][half] 64 KB

    // XCD swizzle (NWG = 2000, divisible by 8)
    const int id = blockIdx.x;
    const int wg = (id & 7) * (NWG/8) + (id >> 3);
    const int mt = wg % NMT;
    const int vt = wg / NMT;

    const int t = threadIdx.x;
    const int w = t >> 6;
    const int lane = t & 63;
    const int r16 = lane & 15;
    const int kb = (lane >> 4) & 3;
    const int wr = w >> 2;          // 0..1
    const int wc = w & 3;           // 0..3
    const int row0 = mt * BM;
    const int v0 = vt * BN;

    // staging decomposition: 8-row groups, pre-swizzled global seg
    const int rr = lane >> 3;            // row within 8-row group
    const int gg = (lane & 7) ^ rr;      // global 16B-seg for slot (lane&7)

    #define STAGE_A(BUF, HLF, KT) do {                                            \
        _Pragma("unroll")                                                         \
        for (int j_ = 0; j_ < 2; ++j_) {                                          \
            int rg_ = w*2 + j_;                                                   \
            GLOAD16(Pb + (size_t)(row0 + (HLF)*128 + rg_*8 + rr)*HH + (KT)*BK + gg*8, \
                    &Alds[BUF][HLF][rg_*512]);                                    \
        }                                                                         \
    } while (0)

    #define STAGE_B(BUF, HLF, KT) do {                                            \
        _Pragma("unroll")                                                         \
        for (int j_ = 0; j_ < 2; ++j_) {                                          \
            int rg_ = w*2 + j_;                                                   \
            GLOAD16(Wt + (size_t)(v0 + (HLF)*128 + rg_*8 + rr)*HH + (KT)*BK + gg*8, \
                    &Blds[BUF][HLF][rg_*512]);                                    \
        }                                                                         \
    } while (0)

    // prologue: B(0), A(0), B(1)  (12 loads/thread in FIFO order)
    STAGE_B(0, 0, 0); STAGE_B(0, 1, 0);
    STAGE_A(0, 0, 0); STAGE_A(0, 1, 0);
    STAGE_B(1, 0, 1); STAGE_B(1, 1, 1);

    f32x4 acc[8][4];
    #pragma unroll
    for (int mf = 0; mf < 8; ++mf)
        #pragma unroll
        for (int nf = 0; nf < 4; ++nf)
            acc[mf][nf] = (f32x4){0.f, 0.f, 0.f, 0.f};

    asm volatile("s_waitcnt vmcnt(4)" ::: "memory");   // A(0),B(0) arrived; B(1) in flight
    __builtin_amdgcn_s_barrier();

    for (int kt = 0; kt < NKT; ++kt) {
        const int buf = kt & 1;
        const unsigned short* Abase = &Alds[buf][wr][0];
        const unsigned short* Bbase = &Blds[buf][wc >> 1][0];
        const int bcol = (wc & 1) * 64;

        short8 bfr[4][2];
        #pragma unroll
        for (int ph = 0; ph < 2; ++ph) {
            // ---- ds-read this phase's register subtile ----
            if (ph == 0) {
                #pragma unroll
                for (int nf = 0; nf < 4; ++nf)
                    #pragma unroll
                    for (int ks = 0; ks < 2; ++ks) {
                        int col = bcol + nf*16 + r16;
                        bfr[nf][ks] = *(const short8*)
                            &Bbase[col*64 + ((ks*4 + kb) ^ (r16 & 7))*8];
                    }
            }
            short8 afr[4][2];
            #pragma unroll
            for (int i = 0; i < 4; ++i)
                #pragma unroll
                for (int ks = 0; ks < 2; ++ks) {
                    int row = (ph*4 + i)*16 + r16;
                    afr[i][ks] = *(const short8*)
                        &Abase[row*64 + ((ks*4 + kb) ^ (r16 & 7))*8];
                }
            asm volatile("" ::: "memory");

            // ---- stage: ph0 = A(t+1) both halves, ph1 = B(t+2) both halves ----
            if (ph == 0) {
                if (kt + 1 < NKT) { STAGE_A(buf ^ 1, 0, kt + 1); STAGE_A(buf ^ 1, 1, kt + 1); }
            } else {
                if (kt + 2 < NKT) { STAGE_B(buf,     0, kt + 2); STAGE_B(buf,     1, kt + 2); }
            }

            __builtin_amdgcn_s_barrier();
            asm volatile("s_waitcnt lgkmcnt(0)" ::: "memory");
            __builtin_amdgcn_sched_barrier(0);
            __builtin_amdgcn_s_setprio(1);
            #pragma unroll
            for (int ks = 0; ks < 2; ++ks)
                #pragma unroll
                for (int i = 0; i < 4; ++i)
                    #pragma unroll
                    for (int nf = 0; nf < 4; ++nf)
                        acc[ph*4 + i][nf] = __builtin_amdgcn_mfma_f32_16x16x32_bf16(
                            afr[i][ks], bfr[nf][ks], acc[ph*4 + i][nf], 0, 0, 0);
            __builtin_amdgcn_s_setprio(0);
            if (ph == 1) {
                if (kt == NKT - 2)     asm volatile("s_waitcnt vmcnt(0)" ::: "memory");
                else if (kt < NKT - 2) asm volatile("s_waitcnt vmcnt(4)" ::: "memory");
            }
            __builtin_amdgcn_s_barrier();
        }
    }

    // epilogue: bias + per-row max/sumexp over this wave's 64 cols (one chunk)
    const int cchunk = vt*4 + wc;
    float bias[4];
    #pragma unroll
    for (int nf = 0; nf < 4; ++nf) bias[nf] = bc[v0 + wc*64 + nf*16 + r16];

    #pragma unroll
    for (int mf = 0; mf < 8; ++mf) {
        #pragma unroll
        for (int j = 0; j < 4; ++j) {
            const int row = row0 + wr*128 + mf*16 + kb*4 + j;
            float v[4]; float mx = -INFINITY;
            #pragma unroll
            for (int nf = 0; nf < 4; ++nf) {
                v[nf] = acc[mf][nf][j] + bias[nf];
                mx = fmaxf(mx, v[nf]);
            }
            #pragma unroll
            for (int off = 1; off < 16; off <<= 1)
                mx = fmaxf(mx, __shfl_xor(mx, off, 16));
            float se = 0.f;
            #pragma unroll
            for (int nf = 0; nf < 4; ++nf) se += __expf(v[nf] - mx);
            #pragma unroll
            for (int off = 1; off < 16; off <<= 1)
                se += __shfl_xor(se, off, 16);
            if (r16 == 0) {
                pmax[(size_t)row*NCHUNK + cchunk] = mx;
                psum[(size_t)row*NCHUNK + cchunk] = se;
            }
            int tg = targets[row];
            int base = v0 + wc*64 + r16;
            #pragma unroll
            for (int nf = 0; nf < 4; ++nf)
                if (tg == base + nf*16) tlogit[row] = v[nf];
        }
    }
}

// ---------------- combine chunk partials -> per-row loss ----------------
__global__ __launch_bounds__(256) void reduce_kernel(
    const float* __restrict__ pmax, const float* __restrict__ psum,
    const float* __restrict__ tlogit, const int* __restrict__ targets,
    float* __restrict__ rowloss)
{
    const int row = blockIdx.x;
    const int tid = threadIdx.x;
    float m0 = (tid       < NCHUNK) ? pmax[(size_t)row*NCHUNK + tid]       : -INFINITY;
    float m1 = (tid + 256 < NCHUNK) ? pmax[(size_t)row*NCHUNK + tid + 256] : -INFINITY;
    float mw = fmaxf(m0, m1);
    #pragma unroll
    for (int off = 1; off < 64; off <<= 1)
        mw = fmaxf(mw, __shfl_xor(mw, off));
    __shared__ float smax[4];
    __shared__ float ssum[4];
    const int wave = tid >> 6;
    if ((tid & 63) == 0) smax[wave] = mw;
    __syncthreads();
    float mx = fmaxf(fmaxf(smax[0], smax[1]), fmaxf(smax[2], smax[3]));
    float s = 0.f;
    if (tid       < NCHUNK) s += psum[(size_t)row*NCHUNK + tid]       * __expf(m0 - mx);
    if (tid + 256 < NCHUNK) s += psum[(size_t)row*NCHUNK + tid + 256] * __expf(m1 - mx);
    #pragma unroll
    for (int off = 1; off < 64; off <<= 1)
        s += __shfl_xor(s, off);
    if ((tid & 63) == 0) ssum[wave] = s;
    __syncthreads();
    if (tid == 0) {
        float st = ssum[0] + ssum[1] + ssum[2] + ssum[3];
        float lse = mx + logf(st);
        int tg = targets[row];
        rowloss[row] = (tg != 0) ? (lse - tlogit[row]) : 0.0f;
    }
}

// ---------------- final sum over rows ----------------
__global__ __launch_bounds__(256) void finalize_kernel(
    const float* __restrict__ rowloss, const int* __restrict__ targets,
    float* __restrict__ out)
{
    const int tid = threadIdx.x;
    float s = 0.f; float c = 0.f;
    for (int i = tid; i < NROWS; i += 256) {
        s += rowloss[i];
        c += (targets[i] != 0) ? 1.0f : 0.0f;
    }
    #pragma unroll
    for (int off = 1; off < 64; off <<= 1) {
        s += __shfl_xor(s, off);
        c += __shfl_xor(c, off);
    }
    __shared__ float ss[4], sc[4];
    const int wave = tid >> 6;
    if ((tid & 63) == 0) { ss[wave] = s; sc[wave] = c; }
    __syncthreads();
    if (tid == 0) {
        float st = ss[0]+ss[1]+ss[2]+ss[3];
        float ct = sc[0]+sc[1]+sc[2]+sc[3];
        out[0] = st / fmaxf(ct, 1.0f);
    }
}

extern "C" void kernel_launch(void* const* d_in, const int* in_sizes, int n_in,
                              void* d_out, int out_size, void* d_ws, size_t ws_size,
                              hipStream_t stream) {
    const float* h       = (const float*)d_in[0];   // (16,512,768) f32
    const int*   wid     = (const int*)  d_in[1];   // (16,512) i32
    const int*   targets = (const int*)  d_in[2];   // (16,256) i32
    const float* Wc      = (const float*)d_in[3];   // (768,32000) f32
    const float* bc      = (const float*)d_in[4];   // (32000,) f32
    float* out = (float*)d_out;

    unsigned short* pooled = (unsigned short*)d_ws;              // 4096*768 bf16
    unsigned short* Wt     = pooled + (size_t)NROWS*HH;          // 32000*768 bf16
    float* pmax  = (float*)(Wt + (size_t)HH*VV);                 // 4096*500
    float* psum  = pmax + (size_t)NROWS*NCHUNK;                  // 4096*500
    float* tlog  = psum + (size_t)NROWS*NCHUNK;                  // 4096
    float* rowl  = tlog + NROWS;                                 // 4096

    pool_kernel<<<NROWS, 256, 0, stream>>>(h, wid, pooled);
    wt_kernel<<<dim3(VV/64, HH/64), 256, 0, stream>>>(Wc, Wt);
    logits_kernel<<<NWG, 512, 0, stream>>>(
        pooled, Wt, bc, targets, pmax, psum, tlog);
    reduce_kernel<<<NROWS, 256, 0, stream>>>(pmax, psum, tlog, targets, rowl);
    finalize_kernel<<<1, 256, 0, stream>>>(rowl, targets, out);
}